// Round 4
// baseline (792.655 us; speedup 1.0000x reference)
//
#include <hip/hip_runtime.h>
#include <hip/hip_bf16.h>

// GroupNLMSMemory: B=512, D=256, M=100000
// out = [retrieved 512x256 | attn 512x100000] (f32)
// No-max softmax (logits in [-10,10]). Path A (ws >= 135MB, proven):
//   k0,k0c(Kbf16+rkn),k0b(VT) -> k1b(sum) -> k2 -> k3<NORM> -> k4
// Path B fallback: k0,k0c,k0b -> k3(unnorm+sums) -> k2 -> k5,k4
// r4: revert r3's atomics + NT stores (latency pathology: MfmaUtil 4%, all
//     pipes idle at 490us). Keep 64-row blocks (2 blk/CU) + XCD grouping
//     (FETCH 203->64MB proven). 56 chunks -> plain-store partials, no k0z.

#define MCOLS 100000
#define MP    100032
#define DDIM  256
#define CHUNK 1792                // 28 tiles of 64
#define NTFULL 28
#define NCHUNK 56                 // 56*1792 = 100352 >= 100000
#define NSLOT  56                 // one partial slot per chunk (plain stores)
#define NST2   112                // NCHUNK*2 sum entries
#define ATTN_OFF 131072
#define WS_RXN  0
#define WS_RKN  512
#define WS_RCPL 100512
#define WS_VT_BYTE   1048576ull
#define WS_VT_END    (WS_VT_BYTE + 2ull*DDIM*MP)            // 52,264,960
#define WS_PART_BYTE 52264960ull
#define WS_PART_END  (WS_PART_BYTE + 4ull*NSLOT*512*256)    // 81,625,088
#define WS_KB_BYTE   84246528ull
#define WS_KB_END    (WS_KB_BYTE + 2ull*(size_t)MCOLS*DDIM) // 135,446,528

typedef short short8 __attribute__((ext_vector_type(8)));
typedef float f32x4  __attribute__((ext_vector_type(4)));

static __device__ __forceinline__ unsigned short f2bfu(float f) {
  union { __hip_bfloat16 h; unsigned short u; } cv;
  cv.h = __float2bfloat16(f);
  return cv.u;
}
static __device__ __forceinline__ unsigned int pk2(float a, float b) {
  return (unsigned int)f2bfu(a) | ((unsigned int)f2bfu(b) << 16);
}
static __device__ __forceinline__ short8 pack8(float4 a, float4 b) {
  short8 r;
  r[0] = (short)f2bfu(a.x); r[1] = (short)f2bfu(a.y);
  r[2] = (short)f2bfu(a.z); r[3] = (short)f2bfu(a.w);
  r[4] = (short)f2bfu(b.x); r[5] = (short)f2bfu(b.y);
  r[6] = (short)f2bfu(b.z); r[7] = (short)f2bfu(b.w);
  return r;
}

// ---------------- k0: x row norms (folds TEMP=10) ----------------
__global__ void k0_xn(const float* __restrict__ x, float* __restrict__ ws) {
  const int b = blockIdx.x, t = threadIdx.x;
  const float v = x[b*DDIM + t];
  float s = v*v;
  #pragma unroll
  for (int mk = 1; mk <= 32; mk <<= 1) s += __shfl_xor(s, mk);
  __shared__ float ps[4];
  if ((t & 63) == 0) ps[t >> 6] = s;
  __syncthreads();
  if (t == 0) {
    const float tot = ps[0] + ps[1] + ps[2] + ps[3];
    ws[WS_RXN + b] = 10.0f / fmaxf(sqrtf(tot), 1e-12f);
  }
}

// ---------------- k0c: K row norms (+ optional Kbf16) ----------------
template<bool WRITEKB>
__global__ __launch_bounds__(256) void k0c_kn(const float* __restrict__ K,
                                              float* __restrict__ ws) {
  const int t = threadIdx.x;
  const int mg = blockIdx.x*64 + (t >> 2);
  const int qq = t & 3;
  if (mg >= MCOLS) return;
  const float* kp = K + (size_t)mg*DDIM + 64*qq;
  unsigned int* kb = (unsigned int*)((char*)ws + WS_KB_BYTE);
  float ss = 0.f;
  #pragma unroll
  for (int j = 0; j < 8; ++j) {
    const float4 a = *(const float4*)(kp + 8*j);
    const float4 b = *(const float4*)(kp + 8*j + 4);
    ss += a.x*a.x + a.y*a.y + a.z*a.z + a.w*a.w
        + b.x*b.x + b.y*b.y + b.z*b.z + b.w*b.w;
    if (WRITEKB) {
      uint4 u;
      u.x = pk2(a.x, a.y); u.y = pk2(a.z, a.w);
      u.z = pk2(b.x, b.y); u.w = pk2(b.z, b.w);
      *(uint4*)(kb + (size_t)mg*128 + 32*qq + 4*j) = u;
    }
  }
  ss += __shfl_xor(ss, 1); ss += __shfl_xor(ss, 2);
  if (qq == 0) ws[WS_RKN + mg] = 1.0f / fmaxf(sqrtf(ss), 1e-12f);
}

// ---------------- k0b: transpose V -> VT bf16 [256][MP] ----------------
__global__ __launch_bounds__(256) void k0b_tr(const float* __restrict__ V,
                                              float* __restrict__ ws) {
  const int t = threadIdx.x;
  const int m0 = blockIdx.x * 64;
  __shared__ float vt_f[64][261];
  #pragma unroll
  for (int i = 0; i < 4; ++i) {
    const int ml = (t >> 4) + 16*i;
    const int mg = m0 + ml;
    #pragma unroll
    for (int j = 0; j < 4; ++j) {
      const int d = 4*(t & 15) + 64*j;
      float4 v = make_float4(0.f, 0.f, 0.f, 0.f);
      if (mg < MCOLS) v = *(const float4*)(V + (size_t)mg*DDIM + d);
      vt_f[ml][d] = v.x; vt_f[ml][d+1] = v.y; vt_f[ml][d+2] = v.z; vt_f[ml][d+3] = v.w;
    }
  }
  __syncthreads();
  unsigned short* vt = (unsigned short*)((char*)ws + WS_VT_BYTE);
  const int mq = 4*(t & 15);
  #pragma unroll
  for (int it = 0; it < 16; ++it) {
    const int d = (t >> 4) + 16*it;
    uint2 u;
    u.x = pk2(vt_f[mq+0][d], vt_f[mq+1][d]);
    u.y = pk2(vt_f[mq+2][d], vt_f[mq+3][d]);
    *(uint2*)(vt + (size_t)d*MP + m0 + mq) = u;
  }
}

// ---------------- k1b (path A): sum-of-exp, 64-row blocks ----------------
__global__ __launch_bounds__(512, 4) void k1b_sum(const float* __restrict__ x,
                                                  const float* __restrict__ ws,
                                                  float* __restrict__ out) {
  const int lin = blockIdx.x;                 // 448 = 8 XCD * 8 rb * 7 chunks
  const int g = lin & 7, j = lin >> 3;
  const int rb = j & 7, c = g*7 + (j >> 3);   // same-chunk blocks on same XCD
  const int t = threadIdx.x, w = t >> 6, l = t & 63, q = l >> 4, ln = l & 15;
  const int ar = w & 3, h = w >> 2;
  const int R0 = rb*64;
  short8 xf[8];
  {
    const int row = R0 + 16*ar + ln;
    #pragma unroll
    for (int kk = 0; kk < 8; ++kk) {
      const float* p = x + row*DDIM + 32*kk + 8*q;
      xf[kk] = pack8(*(const float4*)p, *(const float4*)(p + 4));
    }
  }
  float rxn[4];
  #pragma unroll
  for (int r = 0; r < 4; ++r)
    rxn[r] = ws[WS_RXN + R0 + 16*ar + 4*q + r];
  const unsigned short* kb = (const unsigned short*)((const char*)ws + WS_KB_BYTE);
  const float* rknw = ws + WS_RKN;
  float lpr[4] = {0.f,0.f,0.f,0.f};
  const int mbase = c*CHUNK;
  const int nt = min(NTFULL, (MCOLS - mbase + 63) >> 6);
  for (int mt = 0; mt < nt; ++mt) {
    const int m0 = mbase + mt*64;
    const int mr0 = m0 + 32*h + ln, mr1 = mr0 + 16;
    const int kr0 = min(mr0, MCOLS-1), kr1 = min(mr1, MCOLS-1);
    const unsigned short* p0 = kb + (size_t)kr0*DDIM + 8*q;
    const unsigned short* p1 = kb + (size_t)kr1*DDIM + 8*q;
    f32x4 acc[2];
    { f32x4 z = {0.f,0.f,0.f,0.f}; acc[0] = z; acc[1] = z; }
    #pragma unroll
    for (int kk = 0; kk < 8; ++kk) {
      const short8 b0 = *(const short8*)(p0 + 32*kk);
      const short8 b1 = *(const short8*)(p1 + 32*kk);
      acc[0] = __builtin_amdgcn_mfma_f32_16x16x32_bf16(xf[kk], b0, acc[0], 0,0,0);
      acc[1] = __builtin_amdgcn_mfma_f32_16x16x32_bf16(xf[kk], b1, acc[1], 0,0,0);
    }
    const float rk0 = rknw[kr0], rk1 = rknw[kr1];
    const bool ok0 = mr0 < MCOLS, ok1 = mr1 < MCOLS;
    #pragma unroll
    for (int r = 0; r < 4; ++r)
      lpr[r] += (ok0 ? __expf(acc[0][r]*rxn[r]*rk0) : 0.f)
              + (ok1 ? __expf(acc[1][r]*rxn[r]*rk1) : 0.f);
  }
  #pragma unroll
  for (int r = 0; r < 4; ++r) {
    float s = lpr[r];
    s += __shfl_xor(s, 1); s += __shfl_xor(s, 2);
    s += __shfl_xor(s, 4); s += __shfl_xor(s, 8);
    if (ln == 0)
      out[(size_t)(c*2 + h)*512 + R0 + 16*ar + 4*q + r] = s;
  }
}

// ---------------- k2: merge chunk sums -> 1/l ----------------
__global__ void k2_final(const float* __restrict__ out, float* __restrict__ ws) {
  const int b = blockIdx.x, t = threadIdx.x;   // 512 x 256
  float v = (t < NST2) ? out[(size_t)t*512 + b] : 0.f;
  #pragma unroll
  for (int mk = 1; mk <= 32; mk <<= 1) v += __shfl_xor(v, mk);
  __shared__ float s2[4];
  if ((t & 63) == 0) s2[t >> 6] = v;
  __syncthreads();
  if (t == 0) ws[WS_RCPL + b] = 1.0f / (s2[0] + s2[1] + s2[2] + s2[3]);
}

// ---------------- k3: main fused kernel (64-row blocks) ----------------
template<bool USEKB, bool NORM>
__global__ __launch_bounds__(512, 4) void k3_main(const float* __restrict__ x,
                                                  const float* __restrict__ K,
                                                  float* __restrict__ ws,
                                                  float* __restrict__ out) {
  const int lin = blockIdx.x;                 // 448 = 8 XCD * 8 rb * 7 chunks
  const int g = lin & 7, j = lin >> 3;
  const int rb = j & 7, c = g*7 + (j >> 3);   // same-chunk blocks on same XCD
  const int t = threadIdx.x, w = t >> 6, l = t & 63, q = l >> 4, ln = l & 15;
  const int ar = w & 3, h = w >> 2;           // QK: 16-row strip / 32-col half
  __shared__ __align__(16) unsigned short plds[2][64][72];  // 18.4 KB dbuf
  const int R0 = rb*64;
  short8 xf[8];
  {
    const int row = R0 + 16*ar + ln;
    #pragma unroll
    for (int kk = 0; kk < 8; ++kk) {
      const float* p = x + row*DDIM + 32*kk + 8*q;
      xf[kk] = pack8(*(const float4*)p, *(const float4*)(p + 4));
    }
  }
  float rxn[4], rlq[4];
  #pragma unroll
  for (int r = 0; r < 4; ++r) {
    const int row = R0 + 16*ar + 4*q + r;
    rxn[r] = ws[WS_RXN + row];
    rlq[r] = NORM ? ws[WS_RCPL + row] : 0.f;
  }
  float lpr[4] = {0.f,0.f,0.f,0.f};
  f32x4 apv[8];
  #pragma unroll
  for (int dx = 0; dx < 8; ++dx) { f32x4 z = {0.f,0.f,0.f,0.f}; apv[dx] = z; }
  const int d2 = 128*h;                       // PV: h picks d-half
  const unsigned short* vt = (const unsigned short*)((const char*)ws + WS_VT_BYTE);
  const unsigned short* kb = (const unsigned short*)((const char*)ws + WS_KB_BYTE);
  const float* rknw = ws + WS_RKN;
  float* attn = out + ATTN_OFF;
  const int mbase = c*CHUNK;
  const int nt = min(NTFULL, (MCOLS - mbase + 63) >> 6);

  for (int mt = 0; mt < nt; ++mt) {
    const int m0 = mbase + mt*64;
    short8 bvp[4];                            // PV ks0 prefetch (lands under QK)
    #pragma unroll
    for (int dx = 0; dx < 4; ++dx)
      bvp[dx] = *(const short8*)(vt + (size_t)(d2 + 16*dx + ln)*MP + m0 + 8*q);
    const int mr0 = m0 + 32*h + ln, mr1 = mr0 + 16;
    const int kr0 = min(mr0, MCOLS-1), kr1 = min(mr1, MCOLS-1);
    f32x4 acc[2];
    { f32x4 z = {0.f,0.f,0.f,0.f}; acc[0] = z; acc[1] = z; }
    if (USEKB) {
      const unsigned short* p0 = kb + (size_t)kr0*DDIM + 8*q;
      const unsigned short* p1 = kb + (size_t)kr1*DDIM + 8*q;
      #pragma unroll
      for (int kk = 0; kk < 8; ++kk) {
        const short8 b0 = *(const short8*)(p0 + 32*kk);
        const short8 b1 = *(const short8*)(p1 + 32*kk);
        acc[0] = __builtin_amdgcn_mfma_f32_16x16x32_bf16(xf[kk], b0, acc[0], 0,0,0);
        acc[1] = __builtin_amdgcn_mfma_f32_16x16x32_bf16(xf[kk], b1, acc[1], 0,0,0);
      }
    } else {
      const float* p0 = K + (size_t)kr0*DDIM + 8*q;
      const float* p1 = K + (size_t)kr1*DDIM + 8*q;
      #pragma unroll
      for (int kk = 0; kk < 8; ++kk) {
        const short8 b0 = pack8(*(const float4*)(p0 + 32*kk), *(const float4*)(p0 + 32*kk + 4));
        const short8 b1 = pack8(*(const float4*)(p1 + 32*kk), *(const float4*)(p1 + 32*kk + 4));
        acc[0] = __builtin_amdgcn_mfma_f32_16x16x32_bf16(xf[kk], b0, acc[0], 0,0,0);
        acc[1] = __builtin_amdgcn_mfma_f32_16x16x32_bf16(xf[kk], b1, acc[1], 0,0,0);
      }
    }
    const float rk0 = rknw[kr0], rk1 = rknw[kr1];
    const bool ok0 = mr0 < MCOLS, ok1 = mr1 < MCOLS;
    #pragma unroll
    for (int r = 0; r < 4; ++r) {
      const int rowl = 16*ar + 4*q + r;
      const float p0v = ok0 ? __expf(acc[0][r]*rxn[r]*rk0) : 0.f;
      const float p1v = ok1 ? __expf(acc[1][r]*rxn[r]*rk1) : 0.f;
      float* arow = attn + (size_t)(R0 + rowl)*MCOLS;
      if (NORM) {
        if (ok0) arow[mr0] = p0v*rlq[r];
        if (ok1) arow[mr1] = p1v*rlq[r];
      } else {
        if (ok0) arow[mr0] = p0v;
        if (ok1) arow[mr1] = p1v;
        lpr[r] += p0v + p1v;
      }
      plds[mt & 1][rowl][32*h + ln]      = f2bfu(p0v);
      plds[mt & 1][rowl][32*h + 16 + ln] = f2bfu(p1v);
    }
    __syncthreads();   // single barrier/tile (dbuf: rewrite at mt+2 is safe)
    const unsigned short (*pb)[72] = plds[mt & 1];
    const short8 af0 = *(const short8*)&pb[16*ar + ln][8*q];
    const short8 af1 = *(const short8*)&pb[16*ar + ln][32 + 8*q];
    #pragma unroll
    for (int dx = 0; dx < 4; ++dx)
      apv[dx] = __builtin_amdgcn_mfma_f32_16x16x32_bf16(af0, bvp[dx], apv[dx], 0,0,0);
    #pragma unroll
    for (int dx = 4; dx < 8; ++dx) {
      const short8 bv = *(const short8*)(vt + (size_t)(d2 + 16*dx + ln)*MP + m0 + 8*q);
      apv[dx] = __builtin_amdgcn_mfma_f32_16x16x32_bf16(af0, bv, apv[dx], 0,0,0);
    }
    #pragma unroll
    for (int dx = 0; dx < 8; ++dx) {
      const short8 bv = *(const short8*)(vt + (size_t)(d2 + 16*dx + ln)*MP + m0 + 32 + 8*q);
      apv[dx] = __builtin_amdgcn_mfma_f32_16x16x32_bf16(af1, bv, apv[dx], 0,0,0);
    }
  }

  if (!NORM) {
    #pragma unroll
    for (int r = 0; r < 4; ++r) {
      float s = lpr[r];
      s += __shfl_xor(s, 1); s += __shfl_xor(s, 2);
      s += __shfl_xor(s, 4); s += __shfl_xor(s, 8);
      if (ln == 0)
        out[(size_t)(c*2 + h)*512 + R0 + 16*ar + 4*q + r] = s;
    }
  }
  // plain deterministic partial stores: slot c, rows R0..R0+63 owned by this block
  float* part = (float*)((char*)ws + WS_PART_BYTE);
  float rlp[4];
  #pragma unroll
  for (int r = 0; r < 4; ++r)
    rlp[r] = NORM ? ws[WS_RCPL + R0 + 16*ar + 4*q + r] : 1.f;
  #pragma unroll
  for (int dx = 0; dx < 8; ++dx)
    #pragma unroll
    for (int r = 0; r < 4; ++r)
      part[((size_t)c*512 + R0 + 16*ar + 4*q + r)*256 + d2 + 16*dx + ln]
        = apv[dx][r]*rlp[r];
}

// ---------------- k4: reduce retrieved partials ----------------
template<bool NORM>
__global__ void k4_red(const float* __restrict__ ws, float* __restrict__ out) {
  const int b = blockIdx.x, t = threadIdx.x;
  const float* part = (const float*)((const char*)ws + WS_PART_BYTE);
  float acc = 0.f;
  for (int cc = 0; cc < NSLOT; ++cc)
    acc += part[((size_t)cc*512 + b)*256 + t];
  if (!NORM) acc *= ws[WS_RCPL + b];
  out[b*DDIM + t] = acc;
}

// ---------------- k5 (path B): rescale attn by 1/l ----------------
__global__ void k5_scale(const float* __restrict__ ws, float* __restrict__ out) {
  const int row = blockIdx.y;
  const int i4 = blockIdx.x*256 + threadIdx.x;
  if (i4 >= MCOLS/4) return;
  const float s = ws[WS_RCPL + row];
  float4* p = (float4*)(out + ATTN_OFF + (size_t)row*MCOLS) + i4;
  float4 v = *p;
  v.x *= s; v.y *= s; v.z *= s; v.w *= s;
  *p = v;
}

extern "C" void kernel_launch(void* const* d_in, const int* in_sizes, int n_in,
                              void* d_out, int out_size, void* d_ws, size_t ws_size,
                              hipStream_t stream) {
  const float* x = (const float*)d_in[0];
  const float* K = (const float*)d_in[1];
  const float* V = (const float*)d_in[2];
  float* out = (float*)d_out;
  float* ws  = (float*)d_ws;
  const bool useKB = ws_size >= WS_KB_END;

  k0_xn<<<512, 256, 0, stream>>>(x, ws);
  if (useKB) k0c_kn<true ><<<1563, 256, 0, stream>>>(K, ws);
  else       k0c_kn<false><<<1563, 256, 0, stream>>>(K, ws);
  k0b_tr<<<MP/64, 256, 0, stream>>>(V, ws);
  if (useKB) {                               // Path A
    k1b_sum<<<448, 512, 0, stream>>>(x, ws, out);
    k2_final<<<512, 256, 0, stream>>>(out, ws);
    k3_main<true, true><<<448, 512, 0, stream>>>(x, K, ws, out);
    k4_red<true><<<512, 256, 0, stream>>>(ws, out);
  } else {                                   // Path B
    k3_main<false, false><<<448, 512, 0, stream>>>(x, K, ws, out);
    k2_final<<<512, 256, 0, stream>>>(out, ws);
    k5_scale<<<dim3((MCOLS/4 + 255)/256, 512), 256, 0, stream>>>(ws, out);
    k4_red<false><<<512, 256, 0, stream>>>(ws, out);
  }
}

// Round 5
// 279.214 us; speedup vs baseline: 2.8389x; 2.8389x over previous
//
#include <hip/hip_runtime.h>
#include <hip/hip_bf16.h>

// GroupNLMSMemory: B=512, D=256, M=100000
// out = [retrieved 512x256 | attn 512x100000] (f32)
// r5: r2 topology (128-row blocks, plain dispatch, plain stores) + LDS
//     staging of K-bf16/VT tiles via global_load_lds(16B) with XOR-slot
//     pre-swizzled layouts in ws (conflict-free ds_read_b128 frags).
// Path A (ws >= 135MB, proven r2-r4): k0,k0c<KB>,k0b -> k1b -> k2 -> k3a -> k4
// Path B fallback: k0,k0c,k0b -> k3b(unnorm+sums) -> k2 -> k5,k4

#define MCOLS 100000
#define MP    100032
#define DDIM  256
#define CHUNK 1664                 // k3: 26 tiles of 64, 61 chunks
#define NTFULL 26
#define NCHUNK 61
#define CHUNK1 832                 // k1b: 13 tiles, 121 chunks
#define NCHUNK1 121
#define NST2  242                  // k1b sum entries (121*2)
#define NSLOT 61
#define ATTN_OFF 131072
#define WS_RXN  0
#define WS_RKN  512
#define WS_RCPL 100512
#define WS_VT_BYTE   1048576ull
#define WS_PART_BYTE 52264960ull   // 61*512*256*4 = 31,981,568 -> ends at KB
#define WS_KB_BYTE   84246528ull
#define WS_KB_END    (WS_KB_BYTE + 2ull*(size_t)MCOLS*DDIM) // 135,446,528

#define GLL(g, l) __builtin_amdgcn_global_load_lds( \
    (const __attribute__((address_space(1))) void*)(g), \
    (__attribute__((address_space(3))) void*)(l), 16, 0, 0)

typedef short short8 __attribute__((ext_vector_type(8)));
typedef float f32x4  __attribute__((ext_vector_type(4)));

static __device__ __forceinline__ unsigned short f2bfu(float f) {
  union { __hip_bfloat16 h; unsigned short u; } cv;
  cv.h = __float2bfloat16(f);
  return cv.u;
}
static __device__ __forceinline__ unsigned int pk2(float a, float b) {
  return (unsigned int)f2bfu(a) | ((unsigned int)f2bfu(b) << 16);
}
static __device__ __forceinline__ short8 pack8(float4 a, float4 b) {
  short8 r;
  r[0] = (short)f2bfu(a.x); r[1] = (short)f2bfu(a.y);
  r[2] = (short)f2bfu(a.z); r[3] = (short)f2bfu(a.w);
  r[4] = (short)f2bfu(b.x); r[5] = (short)f2bfu(b.y);
  r[6] = (short)f2bfu(b.z); r[7] = (short)f2bfu(b.w);
  return r;
}

// ---------------- k0: x row norms (folds TEMP=10) ----------------
__global__ void k0_xn(const float* __restrict__ x, float* __restrict__ ws) {
  const int b = blockIdx.x, t = threadIdx.x;
  const float v = x[b*DDIM + t];
  float s = v*v;
  #pragma unroll
  for (int mk = 1; mk <= 32; mk <<= 1) s += __shfl_xor(s, mk);
  __shared__ float ps[4];
  if ((t & 63) == 0) ps[t >> 6] = s;
  __syncthreads();
  if (t == 0) {
    const float tot = ps[0] + ps[1] + ps[2] + ps[3];
    ws[WS_RXN + b] = 10.0f / fmaxf(sqrtf(tot), 1e-12f);
  }
}

// ---------------- k0c: K row norms (+ swizzled Kbf16) ----------------
// Kbf16 row mg: logical 16B slot j stored at phys slot j ^ (mg&7).
template<bool WRITEKB>
__global__ __launch_bounds__(256) void k0c_kn(const float* __restrict__ K,
                                              float* __restrict__ ws) {
  const int t = threadIdx.x;
  const int mg = blockIdx.x*64 + (t >> 2);
  const int qq = t & 3;
  if (mg >= MCOLS) return;
  const float* kp = K + (size_t)mg*DDIM + 64*qq;
  unsigned int* kb = (unsigned int*)((char*)ws + WS_KB_BYTE);
  float ss = 0.f;
  #pragma unroll
  for (int j = 0; j < 8; ++j) {
    const float4 a = *(const float4*)(kp + 8*j);
    const float4 b = *(const float4*)(kp + 8*j + 4);
    ss += a.x*a.x + a.y*a.y + a.z*a.z + a.w*a.w
        + b.x*b.x + b.y*b.y + b.z*b.z + b.w*b.w;
    if (WRITEKB) {
      uint4 u;
      u.x = pk2(a.x, a.y); u.y = pk2(a.z, a.w);
      u.z = pk2(b.x, b.y); u.w = pk2(b.z, b.w);
      const int slot = (8*qq + j) ^ (mg & 7);
      *(uint4*)(kb + (size_t)mg*128 + slot*4) = u;
    }
  }
  ss += __shfl_xor(ss, 1); ss += __shfl_xor(ss, 2);
  if (qq == 0) ws[WS_RKN + mg] = 1.0f / fmaxf(sqrtf(ss), 1e-12f);
}

// ---------------- k0b: V -> VT bf16 [256][MP], swizzled ----------------
// VT row d: within each 64-col block, logical 8-col slot s at phys s^(d&7).
__global__ __launch_bounds__(256) void k0b_tr(const float* __restrict__ V,
                                              float* __restrict__ ws) {
  const int t = threadIdx.x;
  const int m0 = blockIdx.x * 64;
  __shared__ float vt_f[64][261];
  #pragma unroll
  for (int i = 0; i < 4; ++i) {
    const int ml = (t >> 4) + 16*i;
    const int mg = m0 + ml;
    #pragma unroll
    for (int j = 0; j < 4; ++j) {
      const int d = 4*(t & 15) + 64*j;
      float4 v = make_float4(0.f, 0.f, 0.f, 0.f);
      if (mg < MCOLS) v = *(const float4*)(V + (size_t)mg*DDIM + d);
      vt_f[ml][d] = v.x; vt_f[ml][d+1] = v.y; vt_f[ml][d+2] = v.z; vt_f[ml][d+3] = v.w;
    }
  }
  __syncthreads();
  unsigned short* vt = (unsigned short*)((char*)ws + WS_VT_BYTE);
  const int tl = t & 15;
  const int s = tl >> 1, hf = tl & 1;       // logical slot s, 8B half hf
  const int mq = 8*s + 4*hf;                // logical col base (within 64)
  #pragma unroll
  for (int it = 0; it < 16; ++it) {
    const int d = (t >> 4) + 16*it;
    uint2 u;
    u.x = pk2(vt_f[mq+0][d], vt_f[mq+1][d]);
    u.y = pk2(vt_f[mq+2][d], vt_f[mq+3][d]);
    const int sp = s ^ (d & 7);
    *(uint2*)(vt + (size_t)d*MP + m0 + sp*8 + 4*hf) = u;
  }
}

// ---------------- shared frag helpers ----------------
static __device__ __forceinline__ void load_xf(const float* __restrict__ x,
                                               int brow0, int q, int ln,
                                               short8 xf[2][8]) {
  #pragma unroll
  for (int as = 0; as < 2; ++as) {
    const int row = brow0 + 16*as + ln;
    #pragma unroll
    for (int kk = 0; kk < 8; ++kk) {
      const float* p = x + row*DDIM + 32*kk + 8*q;
      xf[as][kk] = pack8(*(const float4*)p, *(const float4*)(p + 4));
    }
  }
}

// stage 64 rows x 512B of swizzled Kbf16 into klds[buf] (linear copy)
static __device__ __forceinline__ void stage_k(const char* __restrict__ kb,
                                               int m0, int w, int l,
                                               unsigned short (*klds)[256]) {
  #pragma unroll
  for (int i = 0; i < 4; ++i) {
    int r = m0 + w*8 + i*2 + (l >> 5);
    r = min(r, MCOLS - 1);
    const char* g = kb + (size_t)r*512 + (l & 31)*16;
    char* dst = (char*)&klds[w*8 + i*2][0];
    GLL(g, dst);
  }
}

// stage 256 rows x 128B of swizzled VT into vtl[buf] (linear copy)
static __device__ __forceinline__ void stage_vt(const char* __restrict__ vtb,
                                                int m1, int w, int l,
                                                unsigned short (*vtl)[64]) {
  #pragma unroll
  for (int i = 0; i < 4; ++i) {
    const int d = w*32 + i*8 + (l >> 3);
    const int ms = min(m1 + (l & 7)*8, MP - 8);
    const char* g = vtb + ((size_t)d*MP + ms)*2;
    char* dst = (char*)&vtl[w*32 + i*8][0];
    GLL(g, dst);
  }
}

// ---------------- k1b (path A): sum-of-exp with K LDS staging ----------------
__global__ __launch_bounds__(512, 4) void k1b_sum(const float* __restrict__ x,
                                                  const float* __restrict__ ws,
                                                  float* __restrict__ out) {
  const int bid = blockIdx.x;                 // 484 = 121 chunks * 4 rb (c-major)
  const int c = bid >> 2, rb = bid & 3;
  const int t = threadIdx.x, w = t >> 6, l = t & 63, q = l >> 4, ln = l & 15;
  const int h = w & 1, rg = w >> 1;
  __shared__ __align__(16) unsigned short klds[2][64][256];
  const char* kb = (const char*)ws + WS_KB_BYTE;

  short8 xf[2][8];
  const int brow0 = rb*128 + 32*rg;
  load_xf(x, brow0, q, ln, xf);
  float rxn[2][4];
  #pragma unroll
  for (int as = 0; as < 2; ++as)
    #pragma unroll
    for (int r = 0; r < 4; ++r)
      rxn[as][r] = ws[WS_RXN + brow0 + 16*as + 4*q + r];
  const float* rknw = ws + WS_RKN;
  float lpr[2][4] = {{0.f,0.f,0.f,0.f},{0.f,0.f,0.f,0.f}};
  const int mbase = c*CHUNK1;
  const int nt = min(13, (MCOLS - mbase + 63) >> 6);
  const int l7 = ln & 7;

  stage_k(kb, mbase, w, l, klds[0]);
  __syncthreads();
  for (int mt = 0; mt < nt; ++mt) {
    const int cur = mt & 1;
    const int m0 = mbase + mt*64;
    stage_k(kb, m0 + 64, w, l, klds[cur ^ 1]);
    const char* kbase = (const char*)&klds[cur][0][0];
    const int row0 = 32*h + ln;
    f32x4 acc[2][2];
    #pragma unroll
    for (int as = 0; as < 2; ++as)
      #pragma unroll
      for (int mm = 0; mm < 2; ++mm) { f32x4 z = {0.f,0.f,0.f,0.f}; acc[as][mm] = z; }
    #pragma unroll
    for (int kk = 0; kk < 8; ++kk) {
      const int sl = ((q + 4*kk) ^ l7) << 4;
      const short8 b0 = *(const short8*)(kbase + row0*512 + sl);
      const short8 b1 = *(const short8*)(kbase + (row0 + 16)*512 + sl);
      acc[0][0] = __builtin_amdgcn_mfma_f32_16x16x32_bf16(xf[0][kk], b0, acc[0][0], 0,0,0);
      acc[0][1] = __builtin_amdgcn_mfma_f32_16x16x32_bf16(xf[0][kk], b1, acc[0][1], 0,0,0);
      acc[1][0] = __builtin_amdgcn_mfma_f32_16x16x32_bf16(xf[1][kk], b0, acc[1][0], 0,0,0);
      acc[1][1] = __builtin_amdgcn_mfma_f32_16x16x32_bf16(xf[1][kk], b1, acc[1][1], 0,0,0);
    }
    const int mr0 = m0 + 32*h + ln, mr1 = mr0 + 16;
    const int kr0 = min(mr0, MCOLS-1), kr1 = min(mr1, MCOLS-1);
    const float rk0 = rknw[kr0], rk1 = rknw[kr1];
    const bool ok0 = mr0 < MCOLS, ok1 = mr1 < MCOLS;
    #pragma unroll
    for (int as = 0; as < 2; ++as)
      #pragma unroll
      for (int r = 0; r < 4; ++r)
        lpr[as][r] += (ok0 ? __expf(acc[as][0][r]*rxn[as][r]*rk0) : 0.f)
                    + (ok1 ? __expf(acc[as][1][r]*rxn[as][r]*rk1) : 0.f);
    __syncthreads();
  }
  #pragma unroll
  for (int as = 0; as < 2; ++as)
    #pragma unroll
    for (int r = 0; r < 4; ++r) {
      float s = lpr[as][r];
      s += __shfl_xor(s, 1); s += __shfl_xor(s, 2);
      s += __shfl_xor(s, 4); s += __shfl_xor(s, 8);
      if (ln == 0)
        out[(size_t)(c*2 + h)*512 + brow0 + 16*as + 4*q + r] = s;
    }
}

// ---------------- k2: merge chunk sums -> 1/l ----------------
__global__ void k2_final(const float* __restrict__ out, float* __restrict__ ws) {
  const int b = blockIdx.x, t = threadIdx.x;   // 512 x 256
  float v = (t < NST2) ? out[(size_t)t*512 + b] : 0.f;
  #pragma unroll
  for (int mk = 1; mk <= 32; mk <<= 1) v += __shfl_xor(v, mk);
  __shared__ float s2[4];
  if ((t & 63) == 0) s2[t >> 6] = v;
  __syncthreads();
  if (t == 0) ws[WS_RCPL + b] = 1.0f / (s2[0] + s2[1] + s2[2] + s2[3]);
}

// ---------------- k3a (path A): fused attn-write + PV, LDS-staged ----------------
__global__ __launch_bounds__(512, 2) void k3a_main(const float* __restrict__ x,
                                                   float* __restrict__ ws,
                                                   float* __restrict__ out) {
  const int bid = blockIdx.x;                 // 244 = 61 chunks * 4 rb (c-major)
  const int c = bid >> 2, rb = bid & 3;
  const int t = threadIdx.x, w = t >> 6, l = t & 63, q = l >> 4, ln = l & 15;
  const int h = w & 1, rg = w >> 1;
  __shared__ __align__(16) unsigned short klds[2][64][256];  // 64 KB
  __shared__ __align__(16) unsigned short vtl[2][256][64];   // 64 KB
  __shared__ __align__(16) unsigned short plds[128][72];     // 18 KB
  const char* kb  = (const char*)ws + WS_KB_BYTE;
  const char* vtb = (const char*)ws + WS_VT_BYTE;
  const int R0 = rb*128;

  short8 xf[2][8];
  const int brow0 = R0 + 32*rg;
  load_xf(x, brow0, q, ln, xf);
  float rxn[2][4], rlq[2][4];
  #pragma unroll
  for (int as = 0; as < 2; ++as)
    #pragma unroll
    for (int r = 0; r < 4; ++r) {
      const int row = brow0 + 16*as + 4*q + r;
      rxn[as][r] = ws[WS_RXN  + row];
      rlq[as][r] = ws[WS_RCPL + row];
    }
  f32x4 apv[2][8];
  #pragma unroll
  for (int bs = 0; bs < 2; ++bs)
    #pragma unroll
    for (int dx = 0; dx < 8; ++dx) { f32x4 z = {0.f,0.f,0.f,0.f}; apv[bs][dx] = z; }
  const int b2 = 32*(w & 3), d2 = 128*(w >> 2);
  const float* rknw = ws + WS_RKN;
  float* attn = out + ATTN_OFF;
  const int mbase = c*CHUNK;
  const int nt = min(NTFULL, (MCOLS - mbase + 63) >> 6);
  const int l7 = ln & 7;

  stage_k(kb, mbase, w, l, klds[0]);
  stage_vt(vtb, mbase, w, l, vtl[0]);
  __syncthreads();

  for (int mt = 0; mt < nt; ++mt) {
    const int cur = mt & 1;
    const int m0 = mbase + mt*64;
    stage_k(kb, m0 + 64, w, l, klds[cur ^ 1]);     // overlaps QK phase
    // ---- QK from klds[cur] ----
    const char* kbase = (const char*)&klds[cur][0][0];
    const int row0 = 32*h + ln;
    f32x4 acc[2][2];
    #pragma unroll
    for (int as = 0; as < 2; ++as)
      #pragma unroll
      for (int mm = 0; mm < 2; ++mm) { f32x4 z = {0.f,0.f,0.f,0.f}; acc[as][mm] = z; }
    #pragma unroll
    for (int kk = 0; kk < 8; ++kk) {
      const int sl = ((q + 4*kk) ^ l7) << 4;
      const short8 b0 = *(const short8*)(kbase + row0*512 + sl);
      const short8 b1 = *(const short8*)(kbase + (row0 + 16)*512 + sl);
      acc[0][0] = __builtin_amdgcn_mfma_f32_16x16x32_bf16(xf[0][kk], b0, acc[0][0], 0,0,0);
      acc[0][1] = __builtin_amdgcn_mfma_f32_16x16x32_bf16(xf[0][kk], b1, acc[0][1], 0,0,0);
      acc[1][0] = __builtin_amdgcn_mfma_f32_16x16x32_bf16(xf[1][kk], b0, acc[1][0], 0,0,0);
      acc[1][1] = __builtin_amdgcn_mfma_f32_16x16x32_bf16(xf[1][kk], b1, acc[1][1], 0,0,0);
    }
    const int mr0 = m0 + 32*h + ln, mr1 = mr0 + 16;
    const int kr0 = min(mr0, MCOLS-1), kr1 = min(mr1, MCOLS-1);
    const float rk0 = rknw[kr0], rk1 = rknw[kr1];
    const bool ok0 = mr0 < MCOLS, ok1 = mr1 < MCOLS;
    #pragma unroll
    for (int as = 0; as < 2; ++as)
      #pragma unroll
      for (int r = 0; r < 4; ++r) {
        const int rowl = 32*rg + 16*as + 4*q + r;
        const float p0v = ok0 ? __expf(acc[as][0][r]*rxn[as][r]*rk0) : 0.f;
        const float p1v = ok1 ? __expf(acc[as][1][r]*rxn[as][r]*rk1) : 0.f;
        float* arow = attn + (size_t)(R0 + rowl)*MCOLS;
        if (ok0) arow[mr0] = p0v*rlq[as][r];
        if (ok1) arow[mr1] = p1v*rlq[as][r];
        plds[rowl][32*h + ln]      = f2bfu(p0v);
        plds[rowl][32*h + 16 + ln] = f2bfu(p1v);
      }
    __syncthreads();                                // A: plds + K-stage drained
    stage_vt(vtb, m0 + 64, w, l, vtl[cur ^ 1]);     // overlaps PV phase
    // ---- PV from vtl[cur] + plds ----
    const char* vbase = (const char*)&vtl[cur][0][0];
    const short8 af00 = *(const short8*)&plds[b2 + ln][8*q];
    const short8 af01 = *(const short8*)&plds[b2 + ln][32 + 8*q];
    const short8 af10 = *(const short8*)&plds[b2 + 16 + ln][8*q];
    const short8 af11 = *(const short8*)&plds[b2 + 16 + ln][32 + 8*q];
    const int sl0 = (q ^ l7) << 4, sl1 = ((4 + q) ^ l7) << 4;
    #pragma unroll
    for (int dx = 0; dx < 8; ++dx) {
      const int R = d2 + 16*dx + ln;
      const short8 bv0 = *(const short8*)(vbase + R*128 + sl0);
      const short8 bv1 = *(const short8*)(vbase + R*128 + sl1);
      apv[0][dx] = __builtin_amdgcn_mfma_f32_16x16x32_bf16(af00, bv0, apv[0][dx], 0,0,0);
      apv[0][dx] = __builtin_amdgcn_mfma_f32_16x16x32_bf16(af01, bv1, apv[0][dx], 0,0,0);
      apv[1][dx] = __builtin_amdgcn_mfma_f32_16x16x32_bf16(af10, bv0, apv[1][dx], 0,0,0);
      apv[1][dx] = __builtin_amdgcn_mfma_f32_16x16x32_bf16(af11, bv1, apv[1][dx], 0,0,0);
    }
    __syncthreads();                                // B: VT-stage drained
  }

  float* part = (float*)((char*)ws + WS_PART_BYTE);
  float rlp[2][4];
  #pragma unroll
  for (int bs = 0; bs < 2; ++bs)
    #pragma unroll
    for (int r = 0; r < 4; ++r)
      rlp[bs][r] = ws[WS_RCPL + R0 + b2 + 16*bs + 4*q + r];
  #pragma unroll
  for (int bs = 0; bs < 2; ++bs)
    #pragma unroll
    for (int dx = 0; dx < 8; ++dx)
      #pragma unroll
      for (int r = 0; r < 4; ++r)
        part[((size_t)c*512 + R0 + b2 + 16*bs + 4*q + r)*256 + d2 + 16*dx + ln]
          = apv[bs][dx][r]*rlp[bs][r];
}

// ---------------- k3b (path B fallback): r2 direct-load version ----------------
__global__ __launch_bounds__(512, 2) void k3b_main(const float* __restrict__ x,
                                                   const float* __restrict__ K,
                                                   float* __restrict__ ws,
                                                   float* __restrict__ out) {
  const int bid = blockIdx.x;
  const int c = bid >> 2, rb = bid & 3;
  const int t = threadIdx.x, w = t >> 6, l = t & 63, q = l >> 4, ln = l & 15;
  const int h = w & 1, rg = w >> 1;
  __shared__ __align__(16) unsigned short plds[2][128][72];
  const int R0 = rb*128;
  short8 xf[2][8];
  const int brow0 = R0 + 32*rg;
  load_xf(x, brow0, q, ln, xf);
  float rxn[2][4];
  #pragma unroll
  for (int as = 0; as < 2; ++as)
    #pragma unroll
    for (int r = 0; r < 4; ++r)
      rxn[as][r] = ws[WS_RXN + brow0 + 16*as + 4*q + r];
  float lpr[2][4] = {{0.f,0.f,0.f,0.f},{0.f,0.f,0.f,0.f}};
  f32x4 apv[2][8];
  #pragma unroll
  for (int bs = 0; bs < 2; ++bs)
    #pragma unroll
    for (int dx = 0; dx < 8; ++dx) { f32x4 z = {0.f,0.f,0.f,0.f}; apv[bs][dx] = z; }
  const int b2 = 32*(w & 3), d2 = 128*(w >> 2);
  const unsigned short* vt = (const unsigned short*)((const char*)ws + WS_VT_BYTE);
  const float* rknw = ws + WS_RKN;
  float* attn = out + ATTN_OFF;
  const int mbase = c*CHUNK;
  const int nt = min(NTFULL, (MCOLS - mbase + 63) >> 6);
  const int l7 = ln & 7;

  for (int mt = 0; mt < nt; ++mt) {
    const int m0 = mbase + mt*64;
    const int mr0 = m0 + 32*h + ln, mr1 = mr0 + 16;
    const int kr0 = min(mr0, MCOLS-1), kr1 = min(mr1, MCOLS-1);
    f32x4 acc[2][2];
    #pragma unroll
    for (int as = 0; as < 2; ++as)
      #pragma unroll
      for (int mm = 0; mm < 2; ++mm) { f32x4 z = {0.f,0.f,0.f,0.f}; acc[as][mm] = z; }
    const float* p0 = K + (size_t)kr0*DDIM + 8*q;
    const float* p1 = K + (size_t)kr1*DDIM + 8*q;
    #pragma unroll
    for (int kk = 0; kk < 8; ++kk) {
      const short8 b0 = pack8(*(const float4*)(p0 + 32*kk), *(const float4*)(p0 + 32*kk + 4));
      const short8 b1 = pack8(*(const float4*)(p1 + 32*kk), *(const float4*)(p1 + 32*kk + 4));
      acc[0][0] = __builtin_amdgcn_mfma_f32_16x16x32_bf16(xf[0][kk], b0, acc[0][0], 0,0,0);
      acc[0][1] = __builtin_amdgcn_mfma_f32_16x16x32_bf16(xf[0][kk], b1, acc[0][1], 0,0,0);
      acc[1][0] = __builtin_amdgcn_mfma_f32_16x16x32_bf16(xf[1][kk], b0, acc[1][0], 0,0,0);
      acc[1][1] = __builtin_amdgcn_mfma_f32_16x16x32_bf16(xf[1][kk], b1, acc[1][1], 0,0,0);
    }
    const float rk0 = rknw[kr0], rk1 = rknw[kr1];
    const bool ok0 = mr0 < MCOLS, ok1 = mr1 < MCOLS;
    #pragma unroll
    for (int as = 0; as < 2; ++as)
      #pragma unroll
      for (int r = 0; r < 4; ++r) {
        const int rowl = 32*rg + 16*as + 4*q + r;
        const float p0v = ok0 ? __expf(acc[as][0][r]*rxn[as][r]*rk0) : 0.f;
        const float p1v = ok1 ? __expf(acc[as][1][r]*rxn[as][r]*rk1) : 0.f;
        float* arow = attn + (size_t)(R0 + rowl)*MCOLS;
        if (ok0) arow[mr0] = p0v;
        if (ok1) arow[mr1] = p1v;
        lpr[as][r] += p0v + p1v;
        plds[mt & 1][rowl][32*h + ln]      = f2bfu(p0v);
        plds[mt & 1][rowl][32*h + 16 + ln] = f2bfu(p1v);
      }
    __syncthreads();
    const unsigned short (*pb)[72] = plds[mt & 1];
    const short8 af00 = *(const short8*)&pb[b2 + ln][8*q];
    const short8 af01 = *(const short8*)&pb[b2 + ln][32 + 8*q];
    const short8 af10 = *(const short8*)&pb[b2 + 16 + ln][8*q];
    const short8 af11 = *(const short8*)&pb[b2 + 16 + ln][32 + 8*q];
    #pragma unroll
    for (int dx = 0; dx < 8; ++dx) {
      const int R = d2 + 16*dx + ln;
      const size_t rbase = (size_t)R*MP + m0;
      const short8 bv0 = *(const short8*)(vt + rbase + ((q     ^ (R & 7)) << 3));
      const short8 bv1 = *(const short8*)(vt + rbase + (((4+q) ^ (R & 7)) << 3));
      apv[0][dx] = __builtin_amdgcn_mfma_f32_16x16x32_bf16(af00, bv0, apv[0][dx], 0,0,0);
      apv[0][dx] = __builtin_amdgcn_mfma_f32_16x16x32_bf16(af01, bv1, apv[0][dx], 0,0,0);
      apv[1][dx] = __builtin_amdgcn_mfma_f32_16x16x32_bf16(af10, bv0, apv[1][dx], 0,0,0);
      apv[1][dx] = __builtin_amdgcn_mfma_f32_16x16x32_bf16(af11, bv1, apv[1][dx], 0,0,0);
    }
  }

  #pragma unroll
  for (int as = 0; as < 2; ++as)
    #pragma unroll
    for (int r = 0; r < 4; ++r) {
      float s = lpr[as][r];
      s += __shfl_xor(s, 1); s += __shfl_xor(s, 2);
      s += __shfl_xor(s, 4); s += __shfl_xor(s, 8);
      if (ln == 0)
        out[(size_t)(c*2 + h)*512 + brow0 + 16*as + 4*q + r] = s;
    }
  float* part = (float*)((char*)ws + WS_PART_BYTE);
  #pragma unroll
  for (int bs = 0; bs < 2; ++bs)
    #pragma unroll
    for (int dx = 0; dx < 8; ++dx)
      #pragma unroll
      for (int r = 0; r < 4; ++r)
        part[((size_t)c*512 + R0 + b2 + 16*bs + 4*q + r)*256 + d2 + 16*dx + ln]
          = apv[bs][dx][r];
}

// ---------------- k4: reduce retrieved partials ----------------
template<bool NORM>
__global__ void k4_red(const float* __restrict__ ws, float* __restrict__ out) {
  const int b = blockIdx.x, t = threadIdx.x;
  const float* part = (const float*)((const char*)ws + WS_PART_BYTE);
  float acc = 0.f;
  for (int cc = 0; cc < NSLOT; ++cc)
    acc += part[((size_t)cc*512 + b)*256 + t];
  if (!NORM) acc *= ws[WS_RCPL + b];
  out[b*DDIM + t] = acc;
}

// ---------------- k5 (path B): rescale attn by 1/l ----------------
__global__ void k5_scale(const float* __restrict__ ws, float* __restrict__ out) {
  const int row = blockIdx.y;
  const int i4 = blockIdx.x*256 + threadIdx.x;
  if (i4 >= MCOLS/4) return;
  const float s = ws[WS_RCPL + row];
  float4* p = (float4*)(out + ATTN_OFF + (size_t)row*MCOLS) + i4;
  float4 v = *p;
  v.x *= s; v.y *= s; v.z *= s; v.w *= s;
  *p = v;
}

extern "C" void kernel_launch(void* const* d_in, const int* in_sizes, int n_in,
                              void* d_out, int out_size, void* d_ws, size_t ws_size,
                              hipStream_t stream) {
  const float* x = (const float*)d_in[0];
  const float* K = (const float*)d_in[1];
  const float* V = (const float*)d_in[2];
  float* out = (float*)d_out;
  float* ws  = (float*)d_ws;
  const bool useKB = ws_size >= WS_KB_END;

  k0_xn<<<512, 256, 0, stream>>>(x, ws);
  if (useKB) k0c_kn<true ><<<1563, 256, 0, stream>>>(K, ws);
  else       k0c_kn<false><<<1563, 256, 0, stream>>>(K, ws);
  k0b_tr<<<MP/64, 256, 0, stream>>>(V, ws);
  if (useKB) {                               // Path A
    k1b_sum<<<484, 512, 0, stream>>>(x, ws, out);
    k2_final<<<512, 256, 0, stream>>>(out, ws);
    k3a_main<<<244, 512, 0, stream>>>(x, ws, out);
    k4_red<true><<<512, 256, 0, stream>>>(ws, out);
  } else {                                   // Path B
    k3b_main<<<244, 512, 0, stream>>>(x, K, ws, out);
    k2_final<<<512, 256, 0, stream>>>(out, ws);
    k5_scale<<<dim3((MCOLS/4 + 255)/256, 512), 256, 0, stream>>>(ws, out);
    k4_red<false><<<512, 256, 0, stream>>>(ws, out);
  }
}

// Round 6
// 250.240 us; speedup vs baseline: 3.1676x; 1.1158x over previous
//
#include <hip/hip_runtime.h>
#include <hip/hip_bf16.h>

// GroupNLMSMemory: B=512, D=256, M=100000
// out = [retrieved 512x256 | attn 512x100000] (f32)
// r6: 2 blocks/CU (LDS 73.7KB: single-buffered klds/vtl + 8KB swizzled plds),
//     grid 448 = 56 chunks x 8 row-blocks(64), exact co-XCD chunk grouping,
//     pre-normalized xb=bf16(10*x/|x|), Kbf16=bf16(k/|k|) -> inner loop = exp(acc).
// Path A (ws >= 135.4MB, proven): k0,k0c<KB>,k0b -> k1b -> k2 -> k3a -> k4
// Path B fallback: k0,k0c,k0b -> k3b(unnorm+sums) -> k2 -> k5,k4

#define MCOLS 100000
#define MP    100032
#define DDIM  256
#define CHUNK 1792                 // 28 tiles of 64
#define NTFULL 28
#define NCHUNK 56                  // 56*1792 = 100352 >= 100000 ; 56 = 8 XCD * 7
#define NST2  112                  // NCHUNK*2 sum entries
#define NSLOT 56
#define ATTN_OFF 131072
#define WS_RXN  0
#define WS_RKN  512
#define WS_RCPL 100512
#define WS_XB_BYTE   409600ull     // 512*256 bf16 = 256KB, ends 671744 < 1MB
#define WS_VT_BYTE   1048576ull
#define WS_PART_BYTE 52264960ull   // 56*512*256*4 = 29.36MB, ends 81.6MB < KB
#define WS_KB_BYTE   84246528ull
#define WS_KB_END    (WS_KB_BYTE + 2ull*(size_t)MCOLS*DDIM) // 135,446,528

#define GLL(g, l) __builtin_amdgcn_global_load_lds( \
    (const __attribute__((address_space(1))) void*)(g), \
    (__attribute__((address_space(3))) void*)(l), 16, 0, 0)

typedef short short8 __attribute__((ext_vector_type(8)));
typedef float f32x4  __attribute__((ext_vector_type(4)));

static __device__ __forceinline__ unsigned short f2bfu(float f) {
  union { __hip_bfloat16 h; unsigned short u; } cv;
  cv.h = __float2bfloat16(f);
  return cv.u;
}
static __device__ __forceinline__ unsigned int pk2(float a, float b) {
  return (unsigned int)f2bfu(a) | ((unsigned int)f2bfu(b) << 16);
}
static __device__ __forceinline__ short8 pack8(float4 a, float4 b) {
  short8 r;
  r[0] = (short)f2bfu(a.x); r[1] = (short)f2bfu(a.y);
  r[2] = (short)f2bfu(a.z); r[3] = (short)f2bfu(a.w);
  r[4] = (short)f2bfu(b.x); r[5] = (short)f2bfu(b.y);
  r[6] = (short)f2bfu(b.z); r[7] = (short)f2bfu(b.w);
  return r;
}

// ---------------- k0: x norms -> rxn (path B) + xb = bf16(10*x/|x|) ----------------
__global__ void k0_xn(const float* __restrict__ x, float* __restrict__ ws) {
  const int b = blockIdx.x, t = threadIdx.x;
  const float v = x[b*DDIM + t];
  float s = v*v;
  #pragma unroll
  for (int mk = 1; mk <= 32; mk <<= 1) s += __shfl_xor(s, mk);
  __shared__ float ps[4];
  if ((t & 63) == 0) ps[t >> 6] = s;
  __syncthreads();
  const float tot = ps[0] + ps[1] + ps[2] + ps[3];
  const float r10 = 10.0f / fmaxf(sqrtf(tot), 1e-12f);
  if (t == 0) ws[WS_RXN + b] = r10;
  unsigned short* xbp = (unsigned short*)((char*)ws + WS_XB_BYTE);
  xbp[b*DDIM + t] = f2bfu(v * r10);
}

// ---------------- k0c: K norms (+ normalized swizzled Kbf16) ----------------
template<bool WRITEKB>
__global__ __launch_bounds__(256) void k0c_kn(const float* __restrict__ K,
                                              float* __restrict__ ws) {
  const int t = threadIdx.x;
  const int mg = blockIdx.x*64 + (t >> 2);
  const int qq = t & 3;
  if (mg >= MCOLS) return;
  const float* kp = K + (size_t)mg*DDIM + 64*qq;
  float4 buf[16];
  float ss = 0.f;
  #pragma unroll
  for (int j = 0; j < 16; ++j) {
    buf[j] = *(const float4*)(kp + 4*j);
    ss += buf[j].x*buf[j].x + buf[j].y*buf[j].y + buf[j].z*buf[j].z + buf[j].w*buf[j].w;
  }
  ss += __shfl_xor(ss, 1); ss += __shfl_xor(ss, 2);
  const float rk = 1.0f / fmaxf(sqrtf(ss), 1e-12f);
  if (qq == 0) ws[WS_RKN + mg] = rk;
  if (WRITEKB) {
    unsigned int* kb = (unsigned int*)((char*)ws + WS_KB_BYTE);
    #pragma unroll
    for (int j = 0; j < 8; ++j) {
      const float4 a = buf[2*j], b2 = buf[2*j+1];
      uint4 u;
      u.x = pk2(a.x*rk, a.y*rk);  u.y = pk2(a.z*rk, a.w*rk);
      u.z = pk2(b2.x*rk, b2.y*rk); u.w = pk2(b2.z*rk, b2.w*rk);
      const int slot = (8*qq + j) ^ (mg & 7);   // 16B-slot XOR swizzle
      *(uint4*)(kb + (size_t)mg*128 + slot*4) = u;
    }
  }
}

// ---------------- k0b: V -> VT bf16 [256][MP], slot^(d&7) swizzled ----------------
__global__ __launch_bounds__(256) void k0b_tr(const float* __restrict__ V,
                                              float* __restrict__ ws) {
  const int t = threadIdx.x;
  const int m0 = blockIdx.x * 64;
  __shared__ float vt_f[64][261];
  #pragma unroll
  for (int i = 0; i < 4; ++i) {
    const int ml = (t >> 4) + 16*i;
    const int mg = m0 + ml;
    #pragma unroll
    for (int j = 0; j < 4; ++j) {
      const int d = 4*(t & 15) + 64*j;
      float4 v = make_float4(0.f, 0.f, 0.f, 0.f);
      if (mg < MCOLS) v = *(const float4*)(V + (size_t)mg*DDIM + d);
      vt_f[ml][d] = v.x; vt_f[ml][d+1] = v.y; vt_f[ml][d+2] = v.z; vt_f[ml][d+3] = v.w;
    }
  }
  __syncthreads();
  unsigned short* vt = (unsigned short*)((char*)ws + WS_VT_BYTE);
  const int tl = t & 15;
  const int s = tl >> 1, hf = tl & 1;
  const int mq = 8*s + 4*hf;
  #pragma unroll
  for (int it = 0; it < 16; ++it) {
    const int d = (t >> 4) + 16*it;
    uint2 u;
    u.x = pk2(vt_f[mq+0][d], vt_f[mq+1][d]);
    u.y = pk2(vt_f[mq+2][d], vt_f[mq+3][d]);
    const int sp = s ^ (d & 7);
    *(uint2*)(vt + (size_t)d*MP + m0 + sp*8 + 4*hf) = u;
  }
}

// ---------------- staging helpers (GLL, linear dst) ----------------
static __device__ __forceinline__ void stage_k(const char* __restrict__ kb,
                                               int m0, int w, int l,
                                               unsigned short (*klds)[256]) {
  #pragma unroll
  for (int i = 0; i < 4; ++i) {
    int r = m0 + w*8 + i*2 + (l >> 5);
    r = min(r, MCOLS - 1);
    const char* g = kb + (size_t)r*512 + (l & 31)*16;
    char* dst = (char*)&klds[w*8 + i*2][0];
    GLL(g, dst);
  }
}
static __device__ __forceinline__ void stage_vt(const char* __restrict__ vtb,
                                                int m1, int w, int l,
                                                unsigned short (*vtl)[64]) {
  #pragma unroll
  for (int i = 0; i < 4; ++i) {
    const int d = w*32 + i*8 + (l >> 3);
    const int ms = min(m1 + (l & 7)*8, MP - 8);
    const char* g = vtb + ((size_t)d*MP + ms)*2;
    char* dst = (char*)&vtl[w*32 + i*8][0];
    GLL(g, dst);
  }
}

// ---------------- k1b (path A): sum-of-exp, 64-row blocks, dbuf K ----------------
__global__ __launch_bounds__(512, 4) void k1b_sum(const float* __restrict__ ws,
                                                  float* __restrict__ out) {
  const int bid = blockIdx.x;                 // 448: co-XCD map
  const int xg = bid & 7, i = bid >> 3;
  const int c = xg + 8*(i % 7), rb = i / 7;
  const int t = threadIdx.x, w = t >> 6, l = t & 63, q = l >> 4, ln = l & 15;
  const int ar = w & 3, h = w >> 2, l7 = ln & 7;
  __shared__ __align__(16) unsigned short klds2[2][64][256];  // 64KB
  const char* kb = (const char*)ws + WS_KB_BYTE;
  const unsigned short* xb = (const unsigned short*)((const char*)ws + WS_XB_BYTE);
  const int R0 = rb*64;

  short8 xf[8];
  {
    const int row = R0 + 16*ar + ln;
    #pragma unroll
    for (int kk = 0; kk < 8; ++kk)
      xf[kk] = *(const short8*)(xb + row*DDIM + 32*kk + 8*q);
  }
  float lpr[4] = {0.f,0.f,0.f,0.f};
  const int mbase = c*CHUNK;
  const int nt = min(NTFULL, (MCOLS - mbase + 63) >> 6);

  stage_k(kb, mbase, w, l, klds2[0]);
  __syncthreads();
  for (int mt = 0; mt < nt; ++mt) {
    const int cur = mt & 1;
    const int m0 = mbase + mt*64;
    if (mt + 1 < nt) stage_k(kb, m0 + 64, w, l, klds2[cur ^ 1]);
    const char* kbase = (const char*)&klds2[cur][0][0];
    const int row0 = 32*h + ln;
    f32x4 acc[2];
    { f32x4 z = {0.f,0.f,0.f,0.f}; acc[0] = z; acc[1] = z; }
    #pragma unroll
    for (int kk = 0; kk < 8; ++kk) {
      const int sl = ((q + 4*kk) ^ l7) << 4;
      const short8 b0 = *(const short8*)(kbase + row0*512 + sl);
      const short8 b1 = *(const short8*)(kbase + (row0 + 16)*512 + sl);
      acc[0] = __builtin_amdgcn_mfma_f32_16x16x32_bf16(xf[kk], b0, acc[0], 0,0,0);
      acc[1] = __builtin_amdgcn_mfma_f32_16x16x32_bf16(xf[kk], b1, acc[1], 0,0,0);
    }
    const int mr0 = m0 + row0, mr1 = mr0 + 16;
    const bool ok0 = mr0 < MCOLS, ok1 = mr1 < MCOLS;
    #pragma unroll
    for (int r = 0; r < 4; ++r)
      lpr[r] += (ok0 ? __expf(acc[0][r]) : 0.f) + (ok1 ? __expf(acc[1][r]) : 0.f);
    __syncthreads();
  }
  #pragma unroll
  for (int r = 0; r < 4; ++r) {
    float s = lpr[r];
    s += __shfl_xor(s, 1); s += __shfl_xor(s, 2);
    s += __shfl_xor(s, 4); s += __shfl_xor(s, 8);
    if (ln == 0)
      out[(size_t)(c*2 + h)*512 + R0 + 16*ar + 4*q + r] = s;
  }
}

// ---------------- k2: merge chunk sums -> 1/l ----------------
__global__ void k2_final(const float* __restrict__ out, float* __restrict__ ws) {
  const int b = blockIdx.x, t = threadIdx.x;   // 512 x 128
  float v = (t < NST2) ? out[(size_t)t*512 + b] : 0.f;
  #pragma unroll
  for (int mk = 1; mk <= 32; mk <<= 1) v += __shfl_xor(v, mk);
  __shared__ float s2[2];
  if ((t & 63) == 0) s2[t >> 6] = v;
  __syncthreads();
  if (t == 0) ws[WS_RCPL + b] = 1.0f / (s2[0] + s2[1]);
}

// ---------------- k3a (path A): fused attn-write + PV, 73.7KB LDS ----------------
__global__ __launch_bounds__(512, 4) void k3a_main(float* __restrict__ ws,
                                                   float* __restrict__ out) {
  const int bid = blockIdx.x;                 // 448: co-XCD map
  const int xg = bid & 7, i = bid >> 3;
  const int c = xg + 8*(i % 7), rb = i / 7;
  const int t = threadIdx.x, w = t >> 6, l = t & 63, q = l >> 4, ln = l & 15;
  const int ar = w & 3, h = w >> 2, l7 = ln & 15 & 7;
  __shared__ __align__(16) unsigned short klds[64][256];   // 32KB single
  __shared__ __align__(16) unsigned short vtl[256][64];    // 32KB single
  __shared__ __align__(16) unsigned short plds[64][64];    // 8KB XOR-swizzled
  const char* kb  = (const char*)ws + WS_KB_BYTE;
  const char* vtb = (const char*)ws + WS_VT_BYTE;
  const unsigned short* xb = (const unsigned short*)((const char*)ws + WS_XB_BYTE);
  const int R0 = rb*64;

  short8 xf[8];
  {
    const int row = R0 + 16*ar + ln;
    #pragma unroll
    for (int kk = 0; kk < 8; ++kk)
      xf[kk] = *(const short8*)(xb + row*DDIM + 32*kk + 8*q);
  }
  float rlq[4];
  #pragma unroll
  for (int r = 0; r < 4; ++r)
    rlq[r] = ws[WS_RCPL + R0 + 16*ar + 4*q + r];
  f32x4 apv[8];
  #pragma unroll
  for (int dx = 0; dx < 8; ++dx) { f32x4 z = {0.f,0.f,0.f,0.f}; apv[dx] = z; }
  const int d2 = 128*h;
  float* attn = out + ATTN_OFF;
  const int mbase = c*CHUNK;
  const int nt = min(NTFULL, (MCOLS - mbase + 63) >> 6);
  unsigned short* pf = &plds[0][0];

  stage_k(kb, mbase, w, l, klds);
  __syncthreads();

  for (int mt = 0; mt < nt; ++mt) {
    const int m0 = mbase + mt*64;
    stage_vt(vtb, m0, w, l, vtl);            // VT(t), overlaps QK; drains at bar1
    // ---- QK ----
    const int row0 = 32*h + ln;
    f32x4 acc[2];
    { f32x4 z = {0.f,0.f,0.f,0.f}; acc[0] = z; acc[1] = z; }
    #pragma unroll
    for (int kk = 0; kk < 8; ++kk) {
      const int sl = ((q + 4*kk) ^ l7) << 4;
      const short8 b0 = *(const short8*)((const char*)&klds[0][0] + row0*512 + sl);
      const short8 b1 = *(const short8*)((const char*)&klds[0][0] + (row0 + 16)*512 + sl);
      acc[0] = __builtin_amdgcn_mfma_f32_16x16x32_bf16(xf[kk], b0, acc[0], 0,0,0);
      acc[1] = __builtin_amdgcn_mfma_f32_16x16x32_bf16(xf[kk], b1, acc[1], 0,0,0);
    }
    const int mr0 = m0 + row0, mr1 = mr0 + 16;
    const bool ok0 = mr0 < MCOLS, ok1 = mr1 < MCOLS;
    #pragma unroll
    for (int r = 0; r < 4; ++r) {
      const int rowl = 16*ar + 4*q + r;
      const float p0v = ok0 ? __expf(acc[0][r]) : 0.f;
      const float p1v = ok1 ? __expf(acc[1][r]) : 0.f;
      float* arow = attn + (size_t)(R0 + rowl)*MCOLS;
      if (ok0) arow[mr0] = p0v*rlq[r];
      if (ok1) arow[mr1] = p1v*rlq[r];
      const int r7 = rowl & 7;
      pf[rowl*64 + ((((ln>>3) + 4*h    ) ^ r7) << 3) + (ln & 7)] = f2bfu(p0v);
      pf[rowl*64 + ((((ln>>3) + 4*h + 2) ^ r7) << 3) + (ln & 7)] = f2bfu(p1v);
    }
    __syncthreads();                         // bar1: VT staged, plds ready, klds free
    if (mt + 1 < nt) stage_k(kb, m0 + 64, w, l, klds);  // K(t+1), overlaps PV
    // ---- PV ----
    const int prow = 16*ar + ln;
    const short8 af0 = *(const short8*)(pf + prow*64 + ((q       ^ l7) << 3));
    const short8 af1 = *(const short8*)(pf + prow*64 + (((4 + q) ^ l7) << 3));
    #pragma unroll
    for (int dx = 0; dx < 8; ++dx) {
      const int R = d2 + 16*dx + ln;
      const char* vr = (const char*)&vtl[0][0] + R*128;
      const short8 bv0 = *(const short8*)(vr + ((q       ^ l7) << 4));
      const short8 bv1 = *(const short8*)(vr + (((4 + q) ^ l7) << 4));
      apv[dx] = __builtin_amdgcn_mfma_f32_16x16x32_bf16(af0, bv0, apv[dx], 0,0,0);
      apv[dx] = __builtin_amdgcn_mfma_f32_16x16x32_bf16(af1, bv1, apv[dx], 0,0,0);
    }
    __syncthreads();                         // bar2: vtl reads done, K(t+1) staged
  }

  float* part = (float*)((char*)ws + WS_PART_BYTE);
  #pragma unroll
  for (int dx = 0; dx < 8; ++dx)
    #pragma unroll
    for (int r = 0; r < 4; ++r)
      part[((size_t)c*512 + R0 + 16*ar + 4*q + r)*256 + d2 + 16*dx + ln]
        = apv[dx][r]*rlq[r];
}

// ---------------- k3b (path B fallback): direct-load, unnorm + sums ----------------
static __device__ __forceinline__ void load_xf(const float* __restrict__ x,
                                               int brow0, int q, int ln,
                                               short8 xf[2][8]) {
  #pragma unroll
  for (int as = 0; as < 2; ++as) {
    const int row = brow0 + 16*as + ln;
    #pragma unroll
    for (int kk = 0; kk < 8; ++kk) {
      const float* p = x + row*DDIM + 32*kk + 8*q;
      xf[as][kk] = pack8(*(const float4*)p, *(const float4*)(p + 4));
    }
  }
}

__global__ __launch_bounds__(512, 2) void k3b_main(const float* __restrict__ x,
                                                   const float* __restrict__ K,
                                                   float* __restrict__ ws,
                                                   float* __restrict__ out) {
  const int bid = blockIdx.x;                 // 224 = 56 chunks * 4 rb
  const int c = bid >> 2, rb = bid & 3;
  const int t = threadIdx.x, w = t >> 6, l = t & 63, q = l >> 4, ln = l & 15;
  const int h = w & 1, rg = w >> 1;
  __shared__ __align__(16) unsigned short plds[2][128][72];
  const int R0 = rb*128;
  short8 xf[2][8];
  const int brow0 = R0 + 32*rg;
  load_xf(x, brow0, q, ln, xf);
  float rxn[2][4];
  #pragma unroll
  for (int as = 0; as < 2; ++as)
    #pragma unroll
    for (int r = 0; r < 4; ++r)
      rxn[as][r] = ws[WS_RXN + brow0 + 16*as + 4*q + r];
  float lpr[2][4] = {{0.f,0.f,0.f,0.f},{0.f,0.f,0.f,0.f}};
  f32x4 apv[2][8];
  #pragma unroll
  for (int bs = 0; bs < 2; ++bs)
    #pragma unroll
    for (int dx = 0; dx < 8; ++dx) { f32x4 z = {0.f,0.f,0.f,0.f}; apv[bs][dx] = z; }
  const int b2 = 32*(w & 3), d2 = 128*(w >> 2);
  const unsigned short* vt = (const unsigned short*)((const char*)ws + WS_VT_BYTE);
  const float* rknw = ws + WS_RKN;
  float* attn = out + ATTN_OFF;
  const int mbase = c*CHUNK;
  const int nt = min(NTFULL, (MCOLS - mbase + 63) >> 6);
  const int l7 = ln & 7;

  for (int mt = 0; mt < nt; ++mt) {
    const int m0 = mbase + mt*64;
    const int mr0 = m0 + 32*h + ln, mr1 = mr0 + 16;
    const int kr0 = min(mr0, MCOLS-1), kr1 = min(mr1, MCOLS-1);
    f32x4 acc[2][2];
    #pragma unroll
    for (int as = 0; as < 2; ++as)
      #pragma unroll
      for (int mm = 0; mm < 2; ++mm) { f32x4 z = {0.f,0.f,0.f,0.f}; acc[as][mm] = z; }
    const float* p0 = K + (size_t)kr0*DDIM + 8*q;
    const float* p1 = K + (size_t)kr1*DDIM + 8*q;
    #pragma unroll
    for (int kk = 0; kk < 8; ++kk) {
      const short8 b0 = pack8(*(const float4*)(p0 + 32*kk), *(const float4*)(p0 + 32*kk + 4));
      const short8 b1 = pack8(*(const float4*)(p1 + 32*kk), *(const float4*)(p1 + 32*kk + 4));
      acc[0][0] = __builtin_amdgcn_mfma_f32_16x16x32_bf16(xf[0][kk], b0, acc[0][0], 0,0,0);
      acc[0][1] = __builtin_amdgcn_mfma_f32_16x16x32_bf16(xf[0][kk], b1, acc[0][1], 0,0,0);
      acc[1][0] = __builtin_amdgcn_mfma_f32_16x16x32_bf16(xf[1][kk], b0, acc[1][0], 0,0,0);
      acc[1][1] = __builtin_amdgcn_mfma_f32_16x16x32_bf16(xf[1][kk], b1, acc[1][1], 0,0,0);
    }
    const float rk0 = rknw[kr0], rk1 = rknw[kr1];
    const bool ok0 = mr0 < MCOLS, ok1 = mr1 < MCOLS;
    #pragma unroll
    for (int as = 0; as < 2; ++as)
      #pragma unroll
      for (int r = 0; r < 4; ++r) {
        const int rowl = 32*rg + 16*as + 4*q + r;
        const float p0v = ok0 ? __expf(acc[as][0][r]*rxn[as][r]*rk0) : 0.f;
        const float p1v = ok1 ? __expf(acc[as][1][r]*rxn[as][r]*rk1) : 0.f;
        float* arow = attn + (size_t)(R0 + rowl)*MCOLS;
        if (ok0) arow[mr0] = p0v;
        if (ok1) arow[mr1] = p1v;
        lpr[as][r] += p0v + p1v;
        plds[mt & 1][rowl][32*h + ln]      = f2bfu(p0v);
        plds[mt & 1][rowl][32*h + 16 + ln] = f2bfu(p1v);
      }
    __syncthreads();
    const unsigned short (*pb)[72] = plds[mt & 1];
    const short8 af00 = *(const short8*)&pb[b2 + ln][8*q];
    const short8 af01 = *(const short8*)&pb[b2 + ln][32 + 8*q];
    const short8 af10 = *(const short8*)&pb[b2 + 16 + ln][8*q];
    const short8 af11 = *(const short8*)&pb[b2 + 16 + ln][32 + 8*q];
    #pragma unroll
    for (int dx = 0; dx < 8; ++dx) {
      const int R = d2 + 16*dx + ln;
      const size_t rbase = (size_t)R*MP + m0;
      const short8 bv0 = *(const short8*)(vt + rbase + ((q     ^ (R & 7)) << 3));
      const short8 bv1 = *(const short8*)(vt + rbase + (((4+q) ^ (R & 7)) << 3));
      apv[0][dx] = __builtin_amdgcn_mfma_f32_16x16x32_bf16(af00, bv0, apv[0][dx], 0,0,0);
      apv[0][dx] = __builtin_amdgcn_mfma_f32_16x16x32_bf16(af01, bv1, apv[0][dx], 0,0,0);
      apv[1][dx] = __builtin_amdgcn_mfma_f32_16x16x32_bf16(af10, bv0, apv[1][dx], 0,0,0);
      apv[1][dx] = __builtin_amdgcn_mfma_f32_16x16x32_bf16(af11, bv1, apv[1][dx], 0,0,0);
    }
  }

  #pragma unroll
  for (int as = 0; as < 2; ++as)
    #pragma unroll
    for (int r = 0; r < 4; ++r) {
      float s = lpr[as][r];
      s += __shfl_xor(s, 1); s += __shfl_xor(s, 2);
      s += __shfl_xor(s, 4); s += __shfl_xor(s, 8);
      if (ln == 0)
        out[(size_t)(c*2 + h)*512 + brow0 + 16*as + 4*q + r] = s;
    }
  float* part = (float*)((char*)ws + WS_PART_BYTE);
  #pragma unroll
  for (int bs = 0; bs < 2; ++bs)
    #pragma unroll
    for (int dx = 0; dx < 8; ++dx)
      #pragma unroll
      for (int r = 0; r < 4; ++r)
        part[((size_t)c*512 + R0 + b2 + 16*bs + 4*q + r)*256 + d2 + 16*dx + ln]
          = apv[bs][dx][r];
}

// ---------------- k4: reduce retrieved partials ----------------
template<bool NORM>
__global__ void k4_red(const float* __restrict__ ws, float* __restrict__ out) {
  const int b = blockIdx.x, t = threadIdx.x;
  const float* part = (const float*)((const char*)ws + WS_PART_BYTE);
  float acc = 0.f;
  for (int cc = 0; cc < NSLOT; ++cc)
    acc += part[((size_t)cc*512 + b)*256 + t];
  if (!NORM) acc *= ws[WS_RCPL + b];
  out[b*DDIM + t] = acc;
}

// ---------------- k5 (path B): rescale attn by 1/l ----------------
__global__ void k5_scale(const float* __restrict__ ws, float* __restrict__ out) {
  const int row = blockIdx.y;
  const int i4 = blockIdx.x*256 + threadIdx.x;
  if (i4 >= MCOLS/4) return;
  const float s = ws[WS_RCPL + row];
  float4* p = (float4*)(out + ATTN_OFF + (size_t)row*MCOLS) + i4;
  float4 v = *p;
  v.x *= s; v.y *= s; v.z *= s; v.w *= s;
  *p = v;
}

extern "C" void kernel_launch(void* const* d_in, const int* in_sizes, int n_in,
                              void* d_out, int out_size, void* d_ws, size_t ws_size,
                              hipStream_t stream) {
  const float* x = (const float*)d_in[0];
  const float* K = (const float*)d_in[1];
  const float* V = (const float*)d_in[2];
  float* out = (float*)d_out;
  float* ws  = (float*)d_ws;
  const bool useKB = ws_size >= WS_KB_END;

  k0_xn<<<512, 256, 0, stream>>>(x, ws);
  if (useKB) k0c_kn<true ><<<1563, 256, 0, stream>>>(K, ws);
  else       k0c_kn<false><<<1563, 256, 0, stream>>>(K, ws);
  k0b_tr<<<MP/64, 256, 0, stream>>>(V, ws);
  if (useKB) {                               // Path A
    k1b_sum<<<448, 512, 0, stream>>>(ws, out);
    k2_final<<<512, 128, 0, stream>>>(out, ws);
    k3a_main<<<448, 512, 0, stream>>>(ws, out);
    k4_red<true><<<512, 256, 0, stream>>>(ws, out);
  } else {                                   // Path B
    k3b_main<<<224, 512, 0, stream>>>(x, K, ws, out);
    k2_final<<<512, 128, 0, stream>>>(out, ws);
    k5_scale<<<dim3((MCOLS/4 + 255)/256, 512), 256, 0, stream>>>(ws, out);
    k4_red<false><<<512, 256, 0, stream>>>(ws, out);
  }
}